// Round 14
// baseline (263.095 us; speedup 1.0000x reference)
//
#include <hip/hip_runtime.h>
#include <hip/hip_bf16.h>

#define LN_EPS 1e-5f

typedef __attribute__((ext_vector_type(8))) short short8_t;
typedef __attribute__((ext_vector_type(4))) float float4_t;

__device__ __forceinline__ unsigned short f2bf(float x) {
    unsigned u = __builtin_bit_cast(unsigned, x);
    unsigned r = (u + 0x7FFFu + ((u >> 16) & 1u)) >> 16;
    return (unsigned short)r;
}

__device__ __forceinline__ float bf2f(unsigned short x) {
    return __builtin_bit_cast(float, (unsigned)x << 16);
}

__device__ __forceinline__ float gelu_erf(float p) {
    return 0.5f * p * (1.0f + erff(p * 0.70710678118654752f));
}

// HW packed bf16 atomic add (gfx940+), inline asm to guarantee emission.
__device__ __forceinline__ void atomic_pk_add_bf16_f(unsigned* addr, float lo, float hi) {
    const unsigned pk = (unsigned)f2bf(lo) | ((unsigned)f2bf(hi) << 16);
    unsigned long long a64 = (unsigned long long)addr;
    asm volatile("global_atomic_pk_add_bf16 %0, %1, off"
                 :: "v"(a64), "v"(pk) : "memory");
}

// stage W^T (64 out-cols x 128 k) into swizzled LDS. 256 threads.
__device__ __forceinline__ void stage_w64(const float* __restrict__ W,
                                          unsigned short* Wbuf, int t) {
    const int c  = t & 63;
    const int kb = (t >> 6) * 32;
#pragma unroll
    for (int kk = 0; kk < 32; kk += 8) {
        unsigned short tmp[8];
#pragma unroll
        for (int i = 0; i < 8; ++i)
            tmp[i] = f2bf(W[(size_t)(kb + kk + i) * 64 + c]);
        unsigned idx = (unsigned)(c * 128 + kb + kk) ^ (unsigned)((c & 7) << 3);
        *(uint4*)&Wbuf[idx] = *(const uint4*)tmp;
    }
}

// ================= counting-sort pipeline (by dst) — verified R8 =================
__global__ __launch_bounds__(256) void hist_kernel(
    const int* __restrict__ dst, int* __restrict__ cnt, int E)
{
    const int i = blockIdx.x * blockDim.x + threadIdx.x;
    const int n = gridDim.x * blockDim.x;
    for (int e = i; e < E; e += n) atomicAdd(&cnt[dst[e]], 1);
}

__global__ __launch_bounds__(256) void scanA_kernel(
    const int* __restrict__ cnt, int* __restrict__ off,
    int* __restrict__ bsum, int n)
{
    __shared__ int ls[256];
    const int t = threadIdx.x;
    const int base = blockIdx.x * 1024 + t * 4;
    int v[4];
    int s = 0;
#pragma unroll
    for (int i = 0; i < 4; ++i) {
        v[i] = (base + i < n) ? cnt[base + i] : 0;
        s += v[i];
    }
    ls[t] = s;
    __syncthreads();
    for (int d = 1; d < 256; d <<= 1) {
        int x = (t >= d) ? ls[t - d] : 0;
        __syncthreads();
        ls[t] += x;
        __syncthreads();
    }
    int p = ls[t] - s;
#pragma unroll
    for (int i = 0; i < 4; ++i) {
        if (base + i < n) off[base + i] = p;
        p += v[i];
    }
    if (t == 255) bsum[blockIdx.x] = ls[255];
}

__global__ __launch_bounds__(64) void scanB_kernel(int* __restrict__ bsum, int nb)
{
    const int t = threadIdx.x;
    const int o = (t < nb) ? bsum[t] : 0;
    int v = o;
    for (int d = 1; d < 64; d <<= 1) {
        int x = __shfl_up(v, d);
        if (t >= d) v += x;
    }
    if (t < nb) bsum[t] = v - o;
}

__global__ __launch_bounds__(256) void scatter_kernel(
    const int* __restrict__ dst, int* __restrict__ off,
    const int* __restrict__ bsum, int* __restrict__ perm, int E)
{
    const int i = blockIdx.x * blockDim.x + threadIdx.x;
    const int n = gridDim.x * blockDim.x;
    for (int e = i; e < E; e += n) {
        const int d = dst[e];
        const int p = atomicAdd(&off[d], 1) + bsum[d >> 10];
        perm[p] = e;
    }
}

// ============ Kernel A: hv = LN(GELU(X @ W_node)) -> bf16 ============
__global__ __launch_bounds__(256) void node_proj_kernel(
    const float* __restrict__ X, const float* __restrict__ W,
    const float* __restrict__ g, const float* __restrict__ b,
    unsigned short* __restrict__ outb, int N)
{
    __shared__ __align__(16) unsigned short Wbuf[64 * 128];
    stage_w64(W, Wbuf, threadIdx.x);
    const int lane = threadIdx.x & 63;
    const int r16  = lane & 15;
    const int ks   = (lane >> 4) * 8;
    const int cq   = lane >> 4;
    float gv[4], bv[4];
#pragma unroll
    for (int ct = 0; ct < 4; ++ct) { gv[ct] = g[ct * 16 + r16]; bv[ct] = b[ct * 16 + r16]; }
    __syncthreads();

    const int gw = (int)((blockIdx.x * blockDim.x + threadIdx.x) >> 6);
    const int nw = (int)((gridDim.x * blockDim.x) >> 6);
    const int ntiles = (N + 15) >> 4;
    int tile = gw;
    if (tile >= ntiles) return;

    float4 pf[8];
    {
        const float* base = X + (size_t)min(tile * 16 + r16, N - 1) * 128;
#pragma unroll
        for (int kt = 0; kt < 4; ++kt) {
            pf[2 * kt]     = *(const float4*)(base + kt * 32 + ks);
            pf[2 * kt + 1] = *(const float4*)(base + kt * 32 + ks + 4);
        }
    }

    while (true) {
        const int r0 = tile * 16;
        short8_t a[4];
#pragma unroll
        for (int kt = 0; kt < 4; ++kt) {
            const float4 u = pf[2 * kt], v = pf[2 * kt + 1];
            short8_t t8;
            t8[0] = (short)f2bf(u.x); t8[1] = (short)f2bf(u.y);
            t8[2] = (short)f2bf(u.z); t8[3] = (short)f2bf(u.w);
            t8[4] = (short)f2bf(v.x); t8[5] = (short)f2bf(v.y);
            t8[6] = (short)f2bf(v.z); t8[7] = (short)f2bf(v.w);
            a[kt] = t8;
        }
        const int nt = tile + nw;
        if (nt < ntiles) {
            const float* base = X + (size_t)min(nt * 16 + r16, N - 1) * 128;
#pragma unroll
            for (int kt = 0; kt < 4; ++kt) {
                pf[2 * kt]     = *(const float4*)(base + kt * 32 + ks);
                pf[2 * kt + 1] = *(const float4*)(base + kt * 32 + ks + 4);
            }
        }

        float4_t acc[4];
#pragma unroll
        for (int ct = 0; ct < 4; ++ct) { acc[ct].x = 0.f; acc[ct].y = 0.f; acc[ct].z = 0.f; acc[ct].w = 0.f; }
#pragma unroll
        for (int ct = 0; ct < 4; ++ct) {
            const int c = ct * 16 + r16;
#pragma unroll
            for (int kt = 0; kt < 4; ++kt) {
                unsigned idx = (unsigned)(c * 128 + kt * 32 + ks) ^ (unsigned)((c & 7) << 3);
                short8_t bf = *(const short8_t*)&Wbuf[idx];
                acc[ct] = __builtin_amdgcn_mfma_f32_16x16x32_bf16(a[kt], bf, acc[ct], 0, 0, 0);
            }
        }

#pragma unroll
        for (int j = 0; j < 4; ++j) {
            float p0 = gelu_erf(acc[0][j]), p1 = gelu_erf(acc[1][j]);
            float p2 = gelu_erf(acc[2][j]), p3 = gelu_erf(acc[3][j]);
            float s = (p0 + p1) + (p2 + p3);
            s += __shfl_xor(s, 1); s += __shfl_xor(s, 2);
            s += __shfl_xor(s, 4); s += __shfl_xor(s, 8);
            const float mean = s * (1.0f / 64.0f);
            float d0 = p0 - mean, d1 = p1 - mean, d2 = p2 - mean, d3 = p3 - mean;
            float vs = d0 * d0 + d1 * d1 + d2 * d2 + d3 * d3;
            vs += __shfl_xor(vs, 1); vs += __shfl_xor(vs, 2);
            vs += __shfl_xor(vs, 4); vs += __shfl_xor(vs, 8);
            const float inv = rsqrtf(vs * (1.0f / 64.0f) + LN_EPS);
            const int r = r0 + cq * 4 + j;
            if (r < N) {
                float dd[4] = { d0, d1, d2, d3 };
#pragma unroll
                for (int ct = 0; ct < 4; ++ct)
                    outb[(size_t)r * 64 + ct * 16 + r16] = f2bf(dd[ct] * inv * gv[ct] + bv[ct]);
            }
        }
        if (nt >= ntiles) break;
        tile = nt;
    }
}

// ============ Kernel B: edge — dst-sorted chunk-per-wave, batched + run-merged flush ============
__global__ __launch_bounds__(256) void edge_kernel(
    const float* __restrict__ EF, const float* __restrict__ W,
    const float* __restrict__ g, const float* __restrict__ b,
    const int* __restrict__ src, const int* __restrict__ dst,
    const int* __restrict__ perm,
    const unsigned* __restrict__ hvpk, unsigned* __restrict__ hb, int E)
{
    __shared__ __align__(16) unsigned short Wbuf[64 * 128];
    __shared__ __align__(16) float heL[4][16 * 68];
    __shared__ int srcL[4][16];
    __shared__ int dstL[4][4][16];   // [wave][batch slot][row]
    stage_w64(W, Wbuf, threadIdx.x);
    const int lane = threadIdx.x & 63;
    const int r16  = lane & 15;
    const int ks   = (lane >> 4) * 8;
    const int cq   = lane >> 4;
    const int wv   = threadIdx.x >> 6;
    const int cc   = lane & 31;   // column-pair
    const int hf   = lane >> 5;   // edge parity
    float gv[4], bv[4];
#pragma unroll
    for (int ct = 0; ct < 4; ++ct) { gv[ct] = g[ct * 16 + r16]; bv[ct] = b[ct * 16 + r16]; }
    __syncthreads();

    const int gw  = (int)((blockIdx.x * blockDim.x + threadIdx.x) >> 6);
    const int nwv = (int)((gridDim.x * blockDim.x) >> 6);
    const int ntiles = (E + 15) >> 4;
    const int chunk  = (ntiles + nwv - 1) / nwv;
    const int c0 = gw * chunk;
    const int c1 = min(c0 + chunk, ntiles);
    if (c0 >= c1) return;

    // prologue: prefetch tile c0 (perm -> src/dst/EF)
    float4 pf[8];
    int ps, pd;
    {
        const int pm = perm[min(c0 * 16 + r16, E - 1)];
        const float* base = EF + (size_t)pm * 128;
#pragma unroll
        for (int kt = 0; kt < 4; ++kt) {
            pf[2 * kt]     = *(const float4*)(base + kt * 32 + ks);
            pf[2 * kt + 1] = *(const float4*)(base + kt * 32 + ks + 4);
        }
        ps = src[pm]; pd = dst[pm];
    }

    // run-merge carry (persists across groups within the sorted chunk)
    int   curD = -1;
    float aLo = 0.f, aHi = 0.f;

    for (int gbase = c0; gbase < c1; gbase += 4) {
        const int nb = min(4, c1 - gbase);
        unsigned pkP[4][8];

#pragma unroll
        for (int bslot = 0; bslot < 4; ++bslot) {
            if (bslot < nb) {
                const int tile = gbase + bslot;
                const int e0   = tile * 16;

                if (lane < 16) { srcL[wv][lane] = ps; dstL[wv][bslot][lane] = pd; }

                short8_t a[4];
#pragma unroll
                for (int kt = 0; kt < 4; ++kt) {
                    const float4 u = pf[2 * kt], v = pf[2 * kt + 1];
                    short8_t t8;
                    t8[0] = (short)f2bf(u.x); t8[1] = (short)f2bf(u.y);
                    t8[2] = (short)f2bf(u.z); t8[3] = (short)f2bf(u.w);
                    t8[4] = (short)f2bf(v.x); t8[5] = (short)f2bf(v.y);
                    t8[6] = (short)f2bf(v.z); t8[7] = (short)f2bf(v.w);
                    a[kt] = t8;
                }

                const int nt = tile + 1;
                if (nt < c1) {
                    const int pm = perm[min(nt * 16 + r16, E - 1)];
                    const float* base = EF + (size_t)pm * 128;
#pragma unroll
                    for (int kt = 0; kt < 4; ++kt) {
                        pf[2 * kt]     = *(const float4*)(base + kt * 32 + ks);
                        pf[2 * kt + 1] = *(const float4*)(base + kt * 32 + ks + 4);
                    }
                    ps = src[pm]; pd = dst[pm];
                }

                float4_t acc[4];
#pragma unroll
                for (int ct = 0; ct < 4; ++ct) { acc[ct].x = 0.f; acc[ct].y = 0.f; acc[ct].z = 0.f; acc[ct].w = 0.f; }
#pragma unroll
                for (int ct = 0; ct < 4; ++ct) {
                    const int c = ct * 16 + r16;
#pragma unroll
                    for (int kt = 0; kt < 4; ++kt) {
                        unsigned idx = (unsigned)(c * 128 + kt * 32 + ks) ^ (unsigned)((c & 7) << 3);
                        short8_t bf = *(const short8_t*)&Wbuf[idx];
                        acc[ct] = __builtin_amdgcn_mfma_f32_16x16x32_bf16(a[kt], bf, acc[ct], 0, 0, 0);
                    }
                }

#pragma unroll
                for (int j = 0; j < 4; ++j) {
                    float s = acc[0][j] + acc[1][j] + acc[2][j] + acc[3][j];
                    s += __shfl_xor(s, 1); s += __shfl_xor(s, 2);
                    s += __shfl_xor(s, 4); s += __shfl_xor(s, 8);
                    const float mean = s * (1.0f / 64.0f);
                    float d0 = acc[0][j] - mean, d1 = acc[1][j] - mean;
                    float d2 = acc[2][j] - mean, d3 = acc[3][j] - mean;
                    float vs = d0 * d0 + d1 * d1 + d2 * d2 + d3 * d3;
                    vs += __shfl_xor(vs, 1); vs += __shfl_xor(vs, 2);
                    vs += __shfl_xor(vs, 4); vs += __shfl_xor(vs, 8);
                    const float inv = rsqrtf(vs * (1.0f / 64.0f) + LN_EPS);
                    const int rloc = cq * 4 + j;
                    float dd[4] = { d0, d1, d2, d3 };
#pragma unroll
                    for (int ct = 0; ct < 4; ++ct)
                        heL[wv][rloc * 68 + ct * 16 + r16] = __expf(dd[ct] * inv * gv[ct] + bv[ct]);
                }

                // products -> registers (bf16-pk; zero for padded edges)
#pragma unroll
                for (int u = 0; u < 8; ++u) {
                    const int er = u * 2 + hf;
                    const int s  = srcL[wv][er];
                    const unsigned hvd = hvpk[(size_t)s * 32 + cc];
                    const float2 he2 = *(const float2*)&heL[wv][er * 68 + 2 * cc];
                    float lo = he2.x * bf2f((unsigned short)(hvd & 0xFFFFu));
                    float hi = he2.y * bf2f((unsigned short)(hvd >> 16));
                    if (e0 + er >= E) { lo = 0.f; hi = 0.f; }
                    pkP[bslot][u] = (unsigned)f2bf(lo) | ((unsigned)f2bf(hi) << 16);
                }
            }
        }

        // -------- flush: run-merged atomic burst (dst-sorted => runs contiguous) --------
#pragma unroll
        for (int bslot = 0; bslot < 4; ++bslot) {
            if (bslot < nb) {
#pragma unroll
                for (int u = 0; u < 8; ++u) {
                    const int er = u * 2 + hf;
                    const int d  = dstL[wv][bslot][er];
                    const unsigned pk = pkP[bslot][u];
                    const float lo = bf2f((unsigned short)(pk & 0xFFFFu));
                    const float hi = bf2f((unsigned short)(pk >> 16));
                    if (d != curD) {
                        if (curD >= 0)
                            atomic_pk_add_bf16_f(hb + (size_t)curD * 32 + cc, aLo, aHi);
                        curD = d; aLo = lo; aHi = hi;
                    } else { aLo += lo; aHi += hi; }
                }
            }
        }
    }

    // final carry emit
    if (curD >= 0)
        atomic_pk_add_bf16_f(hb + (size_t)curD * 32 + cc, aLo, aHi);
}

// ============ Kernel C: out = LN(GELU(H @ W_out)) — bf16 H input ============
__global__ __launch_bounds__(256) void out_proj_kernel(
    const unsigned short* __restrict__ Hb, const float* __restrict__ W,
    const float* __restrict__ g, const float* __restrict__ b,
    float* __restrict__ out, int N)
{
    __shared__ __align__(16) unsigned short Wbuf[128 * 64];
    {
        const int t  = threadIdx.x;
        const int c  = t & 127;
        const int k0 = (t >> 7) * 32;
#pragma unroll
        for (int kk = 0; kk < 32; kk += 8) {
            unsigned short tmp[8];
#pragma unroll
            for (int i = 0; i < 8; ++i)
                tmp[i] = f2bf(W[(size_t)(k0 + kk + i) * 128 + c]);
            unsigned idx = (unsigned)(c * 64 + k0 + kk) ^ (unsigned)((c & 7) << 3);
            *(uint4*)&Wbuf[idx] = *(const uint4*)tmp;
        }
    }
    const int lane = threadIdx.x & 63;
    const int r16  = lane & 15;
    const int ks   = (lane >> 4) * 8;
    const int cq   = lane >> 4;
    float gv[8], bv[8];
#pragma unroll
    for (int ct = 0; ct < 8; ++ct) { gv[ct] = g[ct * 16 + r16]; bv[ct] = b[ct * 16 + r16]; }
    __syncthreads();

    const int gw = (int)((blockIdx.x * blockDim.x + threadIdx.x) >> 6);
    const int nw = (int)((gridDim.x * blockDim.x) >> 6);
    const int ntiles = (N + 15) >> 4;
    int tile = gw;
    if (tile >= ntiles) return;

    short8_t pa[2];
    {
        const unsigned short* base = Hb + (size_t)min(tile * 16 + r16, N - 1) * 64;
        pa[0] = *(const short8_t*)(base + ks);
        pa[1] = *(const short8_t*)(base + 32 + ks);
    }

    while (true) {
        const int r0 = tile * 16;
        short8_t a[2];
        a[0] = pa[0]; a[1] = pa[1];

        const int nt = tile + nw;
        if (nt < ntiles) {
            const unsigned short* base = Hb + (size_t)min(nt * 16 + r16, N - 1) * 64;
            pa[0] = *(const short8_t*)(base + ks);
            pa[1] = *(const short8_t*)(base + 32 + ks);
        }

        float4_t acc[8];
#pragma unroll
        for (int ct = 0; ct < 8; ++ct) { acc[ct].x = 0.f; acc[ct].y = 0.f; acc[ct].z = 0.f; acc[ct].w = 0.f; }
#pragma unroll
        for (int ct = 0; ct < 8; ++ct) {
            const int c = ct * 16 + r16;
#pragma unroll
            for (int kt = 0; kt < 2; ++kt) {
                unsigned idx = (unsigned)(c * 64 + kt * 32 + ks) ^ (unsigned)((c & 7) << 3);
                short8_t bf = *(const short8_t*)&Wbuf[idx];
                acc[ct] = __builtin_amdgcn_mfma_f32_16x16x32_bf16(a[kt], bf, acc[ct], 0, 0, 0);
            }
        }

#pragma unroll
        for (int j = 0; j < 4; ++j) {
            float p[8];
            float s = 0.f;
#pragma unroll
            for (int ct = 0; ct < 8; ++ct) { p[ct] = gelu_erf(acc[ct][j]); s += p[ct]; }
            s += __shfl_xor(s, 1); s += __shfl_xor(s, 2);
            s += __shfl_xor(s, 4); s += __shfl_xor(s, 8);
            const float mean = s * (1.0f / 128.0f);
            float vs = 0.f;
#pragma unroll
            for (int ct = 0; ct < 8; ++ct) { p[ct] -= mean; vs += p[ct] * p[ct]; }
            vs += __shfl_xor(vs, 1); vs += __shfl_xor(vs, 2);
            vs += __shfl_xor(vs, 4); vs += __shfl_xor(vs, 8);
            const float inv = rsqrtf(vs * (1.0f / 128.0f) + LN_EPS);
            const int r = r0 + cq * 4 + j;
            if (r < N) {
#pragma unroll
                for (int ct = 0; ct < 8; ++ct)
                    out[(size_t)r * 128 + ct * 16 + r16] = p[ct] * inv * gv[ct] + bv[ct];
            }
        }
        if (nt >= ntiles) break;
        tile = nt;
    }
}

extern "C" void kernel_launch(void* const* d_in, const int* in_sizes, int n_in,
                              void* d_out, int out_size, void* d_ws, size_t ws_size,
                              hipStream_t stream) {
    const float* node_feats = (const float*)d_in[0];
    const float* edge_feats = (const float*)d_in[1];
    const int*   src        = (const int*)d_in[2];
    const int*   dst        = (const int*)d_in[3];
    const float* W_node     = (const float*)d_in[4];
    const float* ln_ng      = (const float*)d_in[5];
    const float* ln_nb      = (const float*)d_in[6];
    const float* W_edge     = (const float*)d_in[7];
    const float* ln_eg      = (const float*)d_in[8];
    const float* ln_eb      = (const float*)d_in[9];
    const float* W_out      = (const float*)d_in[10];
    const float* ln_og      = (const float*)d_in[11];
    const float* ln_ob      = (const float*)d_in[12];
    float* out = (float*)d_out;

    const int N = in_sizes[0] / 128;
    const int E = in_sizes[2];

    unsigned short* hvb  = (unsigned short*)d_ws;            // N*64 bf16
    unsigned short* hb   = hvb + (size_t)N * 64;             // N*64 bf16
    int*            cnt  = (int*)(hb + (size_t)N * 64);      // N
    int*            off  = cnt + N;                          // N
    int*            bsum = off + N;                          // 64
    int*            perm = bsum + 64;                        // E

    const int nbA = (N + 1023) >> 10;

    hipMemsetAsync(hb, 0, (size_t)N * 64 * sizeof(unsigned short), stream);
    hipMemsetAsync(cnt, 0, (size_t)N * sizeof(int), stream);
    hist_kernel<<<1024, 256, 0, stream>>>(dst, cnt, E);
    scanA_kernel<<<nbA, 256, 0, stream>>>(cnt, off, bsum, N);
    scanB_kernel<<<1, 64, 0, stream>>>(bsum, nbA);
    scatter_kernel<<<1024, 256, 0, stream>>>(dst, off, bsum, perm, E);
    node_proj_kernel<<<784, 256, 0, stream>>>(node_feats, W_node, ln_ng, ln_nb, hvb, N);
    edge_kernel<<<1024, 256, 0, stream>>>(edge_feats, W_edge, ln_eg, ln_eb,
                                          src, dst, perm,
                                          (const unsigned*)hvb, (unsigned*)hb, E);
    out_proj_kernel<<<784, 256, 0, stream>>>(hb, W_out, ln_og, ln_ob, out, N);
}

// Round 15
// 157.601 us; speedup vs baseline: 1.6694x; 1.6694x over previous
//
#include <hip/hip_runtime.h>
#include <hip/hip_bf16.h>

#define LN_EPS 1e-5f

typedef __attribute__((ext_vector_type(8))) short short8_t;
typedef __attribute__((ext_vector_type(4))) float float4_t;

__device__ __forceinline__ unsigned short f2bf(float x) {
    unsigned u = __builtin_bit_cast(unsigned, x);
    unsigned r = (u + 0x7FFFu + ((u >> 16) & 1u)) >> 16;
    return (unsigned short)r;
}

__device__ __forceinline__ float bf2f(unsigned short x) {
    return __builtin_bit_cast(float, (unsigned)x << 16);
}

__device__ __forceinline__ float gelu_erf(float p) {
    return 0.5f * p * (1.0f + erff(p * 0.70710678118654752f));
}

// HW packed bf16 atomic add (gfx940+), inline asm to guarantee emission.
__device__ __forceinline__ void atomic_pk_add_bf16_pk(unsigned* addr, unsigned pk) {
    unsigned long long a64 = (unsigned long long)addr;
    asm volatile("global_atomic_pk_add_bf16 %0, %1, off"
                 :: "v"(a64), "v"(pk) : "memory");
}

// stage W^T (64 out-cols x 128 k) into swizzled LDS. 256 threads.
__device__ __forceinline__ void stage_w64(const float* __restrict__ W,
                                          unsigned short* Wbuf, int t) {
    const int c  = t & 63;
    const int kb = (t >> 6) * 32;
#pragma unroll
    for (int kk = 0; kk < 32; kk += 8) {
        unsigned short tmp[8];
#pragma unroll
        for (int i = 0; i < 8; ++i)
            tmp[i] = f2bf(W[(size_t)(kb + kk + i) * 64 + c]);
        unsigned idx = (unsigned)(c * 128 + kb + kk) ^ (unsigned)((c & 7) << 3);
        *(uint4*)&Wbuf[idx] = *(const uint4*)tmp;
    }
}

// ============ Kernel A: hv = LN(GELU(X @ W_node)) -> bf16 ============
__global__ __launch_bounds__(256) void node_proj_kernel(
    const float* __restrict__ X, const float* __restrict__ W,
    const float* __restrict__ g, const float* __restrict__ b,
    unsigned short* __restrict__ outb, int N)
{
    __shared__ __align__(16) unsigned short Wbuf[64 * 128];
    stage_w64(W, Wbuf, threadIdx.x);
    const int lane = threadIdx.x & 63;
    const int r16  = lane & 15;
    const int ks   = (lane >> 4) * 8;
    const int cq   = lane >> 4;
    float gv[4], bv[4];
#pragma unroll
    for (int ct = 0; ct < 4; ++ct) { gv[ct] = g[ct * 16 + r16]; bv[ct] = b[ct * 16 + r16]; }
    __syncthreads();

    const int gw = (int)((blockIdx.x * blockDim.x + threadIdx.x) >> 6);
    const int nw = (int)((gridDim.x * blockDim.x) >> 6);
    const int ntiles = (N + 15) >> 4;
    int tile = gw;
    if (tile >= ntiles) return;

    float4 pf[8];
    {
        const float* base = X + (size_t)min(tile * 16 + r16, N - 1) * 128;
#pragma unroll
        for (int kt = 0; kt < 4; ++kt) {
            pf[2 * kt]     = *(const float4*)(base + kt * 32 + ks);
            pf[2 * kt + 1] = *(const float4*)(base + kt * 32 + ks + 4);
        }
    }

    while (true) {
        const int r0 = tile * 16;
        short8_t a[4];
#pragma unroll
        for (int kt = 0; kt < 4; ++kt) {
            const float4 u = pf[2 * kt], v = pf[2 * kt + 1];
            short8_t t8;
            t8[0] = (short)f2bf(u.x); t8[1] = (short)f2bf(u.y);
            t8[2] = (short)f2bf(u.z); t8[3] = (short)f2bf(u.w);
            t8[4] = (short)f2bf(v.x); t8[5] = (short)f2bf(v.y);
            t8[6] = (short)f2bf(v.z); t8[7] = (short)f2bf(v.w);
            a[kt] = t8;
        }
        const int nt = tile + nw;
        if (nt < ntiles) {
            const float* base = X + (size_t)min(nt * 16 + r16, N - 1) * 128;
#pragma unroll
            for (int kt = 0; kt < 4; ++kt) {
                pf[2 * kt]     = *(const float4*)(base + kt * 32 + ks);
                pf[2 * kt + 1] = *(const float4*)(base + kt * 32 + ks + 4);
            }
        }

        float4_t acc[4];
#pragma unroll
        for (int ct = 0; ct < 4; ++ct) { acc[ct].x = 0.f; acc[ct].y = 0.f; acc[ct].z = 0.f; acc[ct].w = 0.f; }
#pragma unroll
        for (int ct = 0; ct < 4; ++ct) {
            const int c = ct * 16 + r16;
#pragma unroll
            for (int kt = 0; kt < 4; ++kt) {
                unsigned idx = (unsigned)(c * 128 + kt * 32 + ks) ^ (unsigned)((c & 7) << 3);
                short8_t bf = *(const short8_t*)&Wbuf[idx];
                acc[ct] = __builtin_amdgcn_mfma_f32_16x16x32_bf16(a[kt], bf, acc[ct], 0, 0, 0);
            }
        }

#pragma unroll
        for (int j = 0; j < 4; ++j) {
            float p0 = gelu_erf(acc[0][j]), p1 = gelu_erf(acc[1][j]);
            float p2 = gelu_erf(acc[2][j]), p3 = gelu_erf(acc[3][j]);
            float s = (p0 + p1) + (p2 + p3);
            s += __shfl_xor(s, 1); s += __shfl_xor(s, 2);
            s += __shfl_xor(s, 4); s += __shfl_xor(s, 8);
            const float mean = s * (1.0f / 64.0f);
            float d0 = p0 - mean, d1 = p1 - mean, d2 = p2 - mean, d3 = p3 - mean;
            float vs = d0 * d0 + d1 * d1 + d2 * d2 + d3 * d3;
            vs += __shfl_xor(vs, 1); vs += __shfl_xor(vs, 2);
            vs += __shfl_xor(vs, 4); vs += __shfl_xor(vs, 8);
            const float inv = rsqrtf(vs * (1.0f / 64.0f) + LN_EPS);
            const int r = r0 + cq * 4 + j;
            if (r < N) {
                float dd[4] = { d0, d1, d2, d3 };
#pragma unroll
                for (int ct = 0; ct < 4; ++ct)
                    outb[(size_t)r * 64 + ct * 16 + r16] = f2bf(dd[ct] * inv * gv[ct] + bv[ct]);
            }
        }
        if (nt >= ntiles) break;
        tile = nt;
    }
}

// ============ Kernel B: edge — chunk-per-wave, batched flush with per-wave stagger ============
__global__ __launch_bounds__(256) void edge_kernel(
    const float* __restrict__ EF, const float* __restrict__ W,
    const float* __restrict__ g, const float* __restrict__ b,
    const int* __restrict__ src, const int* __restrict__ dst,
    const unsigned* __restrict__ hvpk, unsigned* __restrict__ hb, int E)
{
    __shared__ __align__(16) unsigned short Wbuf[64 * 128];
    __shared__ __align__(16) float heL[4][16 * 68];
    __shared__ int srcL[4][16];
    __shared__ int dstL[4][4][16];   // [wave][batch slot][row]
    stage_w64(W, Wbuf, threadIdx.x);
    const int lane = threadIdx.x & 63;
    const int r16  = lane & 15;
    const int ks   = (lane >> 4) * 8;
    const int cq   = lane >> 4;
    const int wv   = threadIdx.x >> 6;
    const int cc   = lane & 31;   // column-pair
    const int hf   = lane >> 5;   // edge parity
    float gv[4], bv[4];
#pragma unroll
    for (int ct = 0; ct < 4; ++ct) { gv[ct] = g[ct * 16 + r16]; bv[ct] = b[ct * 16 + r16]; }
    __syncthreads();

    const int gw  = (int)((blockIdx.x * blockDim.x + threadIdx.x) >> 6);
    const int nwv = (int)((gridDim.x * blockDim.x) >> 6);
    const int ntiles = (E + 15) >> 4;
    const int chunk  = (ntiles + nwv - 1) / nwv;
    const int c0 = gw * chunk;
    const int c1 = min(c0 + chunk, ntiles);
    if (c0 >= c1) return;

    // prologue: prefetch tile c0
    float4 pf[8];
    int ps, pd;
    {
        const float* base = EF + (size_t)min(c0 * 16 + r16, E - 1) * 128;
#pragma unroll
        for (int kt = 0; kt < 4; ++kt) {
            pf[2 * kt]     = *(const float4*)(base + kt * 32 + ks);
            pf[2 * kt + 1] = *(const float4*)(base + kt * 32 + ks + 4);
        }
        const int ei = min(c0 * 16 + r16, E - 1);
        ps = src[ei]; pd = dst[ei];
    }

    // staggered grouping: first group 1..4 tiles by waveId, then groups of 4.
    // Desynchronizes flush phases across co-resident waves so one wave's
    // atomic burst overlaps other waves' compute.
    int gpos = c0;
    int nb   = min((gw & 3) + 1, c1 - c0);

    while (gpos < c1) {
        unsigned pkP[4][8];

#pragma unroll
        for (int bslot = 0; bslot < 4; ++bslot) {
            if (bslot < nb) {
                const int tile = gpos + bslot;
                const int e0   = tile * 16;

                if (lane < 16) { srcL[wv][lane] = ps; dstL[wv][bslot][lane] = pd; }

                short8_t a[4];
#pragma unroll
                for (int kt = 0; kt < 4; ++kt) {
                    const float4 u = pf[2 * kt], v = pf[2 * kt + 1];
                    short8_t t8;
                    t8[0] = (short)f2bf(u.x); t8[1] = (short)f2bf(u.y);
                    t8[2] = (short)f2bf(u.z); t8[3] = (short)f2bf(u.w);
                    t8[4] = (short)f2bf(v.x); t8[5] = (short)f2bf(v.y);
                    t8[6] = (short)f2bf(v.z); t8[7] = (short)f2bf(v.w);
                    a[kt] = t8;
                }

                const int nt = tile + 1;
                if (nt < c1) {
                    const float* base = EF + (size_t)min(nt * 16 + r16, E - 1) * 128;
#pragma unroll
                    for (int kt = 0; kt < 4; ++kt) {
                        pf[2 * kt]     = *(const float4*)(base + kt * 32 + ks);
                        pf[2 * kt + 1] = *(const float4*)(base + kt * 32 + ks + 4);
                    }
                    const int ei = min(nt * 16 + r16, E - 1);
                    ps = src[ei]; pd = dst[ei];
                }

                float4_t acc[4];
#pragma unroll
                for (int ct = 0; ct < 4; ++ct) { acc[ct].x = 0.f; acc[ct].y = 0.f; acc[ct].z = 0.f; acc[ct].w = 0.f; }
#pragma unroll
                for (int ct = 0; ct < 4; ++ct) {
                    const int c = ct * 16 + r16;
#pragma unroll
                    for (int kt = 0; kt < 4; ++kt) {
                        unsigned idx = (unsigned)(c * 128 + kt * 32 + ks) ^ (unsigned)((c & 7) << 3);
                        short8_t bf = *(const short8_t*)&Wbuf[idx];
                        acc[ct] = __builtin_amdgcn_mfma_f32_16x16x32_bf16(a[kt], bf, acc[ct], 0, 0, 0);
                    }
                }

#pragma unroll
                for (int j = 0; j < 4; ++j) {
                    float s = acc[0][j] + acc[1][j] + acc[2][j] + acc[3][j];
                    s += __shfl_xor(s, 1); s += __shfl_xor(s, 2);
                    s += __shfl_xor(s, 4); s += __shfl_xor(s, 8);
                    const float mean = s * (1.0f / 64.0f);
                    float d0 = acc[0][j] - mean, d1 = acc[1][j] - mean;
                    float d2 = acc[2][j] - mean, d3 = acc[3][j] - mean;
                    float vs = d0 * d0 + d1 * d1 + d2 * d2 + d3 * d3;
                    vs += __shfl_xor(vs, 1); vs += __shfl_xor(vs, 2);
                    vs += __shfl_xor(vs, 4); vs += __shfl_xor(vs, 8);
                    const float inv = rsqrtf(vs * (1.0f / 64.0f) + LN_EPS);
                    const int rloc = cq * 4 + j;
                    float dd[4] = { d0, d1, d2, d3 };
#pragma unroll
                    for (int ct = 0; ct < 4; ++ct)
                        heL[wv][rloc * 68 + ct * 16 + r16] = __expf(dd[ct] * inv * gv[ct] + bv[ct]);
                }

                // products -> registers (no atomics in this phase)
#pragma unroll
                for (int u = 0; u < 8; ++u) {
                    const int er = u * 2 + hf;
                    const int s  = srcL[wv][er];
                    const unsigned hvd = hvpk[(size_t)s * 32 + cc];
                    const float2 he2 = *(const float2*)&heL[wv][er * 68 + 2 * cc];
                    float lo = he2.x * bf2f((unsigned short)(hvd & 0xFFFFu));
                    float hi = he2.y * bf2f((unsigned short)(hvd >> 16));
                    if (e0 + er >= E) { lo = 0.f; hi = 0.f; }   // adds 0 -> harmless
                    pkP[bslot][u] = (unsigned)f2bf(lo) | ((unsigned)f2bf(hi) << 16);
                }
            }
        }

        // -------- flush: pure atomic burst, no loads interleaved --------
#pragma unroll
        for (int bslot = 0; bslot < 4; ++bslot) {
            if (bslot < nb) {
#pragma unroll
                for (int u = 0; u < 8; ++u) {
                    const int er = u * 2 + hf;
                    const int d  = dstL[wv][bslot][er];
                    atomic_pk_add_bf16_pk(hb + (size_t)d * 32 + cc, pkP[bslot][u]);
                }
            }
        }

        gpos += nb;
        nb = min(4, c1 - gpos);
    }
}

// ============ Kernel C: out = LN(GELU(H @ W_out)) — bf16 H input ============
__global__ __launch_bounds__(256) void out_proj_kernel(
    const unsigned short* __restrict__ Hb, const float* __restrict__ W,
    const float* __restrict__ g, const float* __restrict__ b,
    float* __restrict__ out, int N)
{
    __shared__ __align__(16) unsigned short Wbuf[128 * 64];
    {
        const int t  = threadIdx.x;
        const int c  = t & 127;
        const int k0 = (t >> 7) * 32;
#pragma unroll
        for (int kk = 0; kk < 32; kk += 8) {
            unsigned short tmp[8];
#pragma unroll
            for (int i = 0; i < 8; ++i)
                tmp[i] = f2bf(W[(size_t)(k0 + kk + i) * 128 + c]);
            unsigned idx = (unsigned)(c * 64 + k0 + kk) ^ (unsigned)((c & 7) << 3);
            *(uint4*)&Wbuf[idx] = *(const uint4*)tmp;
        }
    }
    const int lane = threadIdx.x & 63;
    const int r16  = lane & 15;
    const int ks   = (lane >> 4) * 8;
    const int cq   = lane >> 4;
    float gv[8], bv[8];
#pragma unroll
    for (int ct = 0; ct < 8; ++ct) { gv[ct] = g[ct * 16 + r16]; bv[ct] = b[ct * 16 + r16]; }
    __syncthreads();

    const int gw = (int)((blockIdx.x * blockDim.x + threadIdx.x) >> 6);
    const int nw = (int)((gridDim.x * blockDim.x) >> 6);
    const int ntiles = (N + 15) >> 4;
    int tile = gw;
    if (tile >= ntiles) return;

    short8_t pa[2];
    {
        const unsigned short* base = Hb + (size_t)min(tile * 16 + r16, N - 1) * 64;
        pa[0] = *(const short8_t*)(base + ks);
        pa[1] = *(const short8_t*)(base + 32 + ks);
    }

    while (true) {
        const int r0 = tile * 16;
        short8_t a[2];
        a[0] = pa[0]; a[1] = pa[1];

        const int nt = tile + nw;
        if (nt < ntiles) {
            const unsigned short* base = Hb + (size_t)min(nt * 16 + r16, N - 1) * 64;
            pa[0] = *(const short8_t*)(base + ks);
            pa[1] = *(const short8_t*)(base + 32 + ks);
        }

        float4_t acc[8];
#pragma unroll
        for (int ct = 0; ct < 8; ++ct) { acc[ct].x = 0.f; acc[ct].y = 0.f; acc[ct].z = 0.f; acc[ct].w = 0.f; }
#pragma unroll
        for (int ct = 0; ct < 8; ++ct) {
            const int c = ct * 16 + r16;
#pragma unroll
            for (int kt = 0; kt < 2; ++kt) {
                unsigned idx = (unsigned)(c * 64 + kt * 32 + ks) ^ (unsigned)((c & 7) << 3);
                short8_t bf = *(const short8_t*)&Wbuf[idx];
                acc[ct] = __builtin_amdgcn_mfma_f32_16x16x32_bf16(a[kt], bf, acc[ct], 0, 0, 0);
            }
        }

#pragma unroll
        for (int j = 0; j < 4; ++j) {
            float p[8];
            float s = 0.f;
#pragma unroll
            for (int ct = 0; ct < 8; ++ct) { p[ct] = gelu_erf(acc[ct][j]); s += p[ct]; }
            s += __shfl_xor(s, 1); s += __shfl_xor(s, 2);
            s += __shfl_xor(s, 4); s += __shfl_xor(s, 8);
            const float mean = s * (1.0f / 128.0f);
            float vs = 0.f;
#pragma unroll
            for (int ct = 0; ct < 8; ++ct) { p[ct] -= mean; vs += p[ct] * p[ct]; }
            vs += __shfl_xor(vs, 1); vs += __shfl_xor(vs, 2);
            vs += __shfl_xor(vs, 4); vs += __shfl_xor(vs, 8);
            const float inv = rsqrtf(vs * (1.0f / 128.0f) + LN_EPS);
            const int r = r0 + cq * 4 + j;
            if (r < N) {
#pragma unroll
                for (int ct = 0; ct < 8; ++ct)
                    out[(size_t)r * 128 + ct * 16 + r16] = p[ct] * inv * gv[ct] + bv[ct];
            }
        }
        if (nt >= ntiles) break;
        tile = nt;
    }
}

extern "C" void kernel_launch(void* const* d_in, const int* in_sizes, int n_in,
                              void* d_out, int out_size, void* d_ws, size_t ws_size,
                              hipStream_t stream) {
    const float* node_feats = (const float*)d_in[0];
    const float* edge_feats = (const float*)d_in[1];
    const int*   src        = (const int*)d_in[2];
    const int*   dst        = (const int*)d_in[3];
    const float* W_node     = (const float*)d_in[4];
    const float* ln_ng      = (const float*)d_in[5];
    const float* ln_nb      = (const float*)d_in[6];
    const float* W_edge     = (const float*)d_in[7];
    const float* ln_eg      = (const float*)d_in[8];
    const float* ln_eb      = (const float*)d_in[9];
    const float* W_out      = (const float*)d_in[10];
    const float* ln_og      = (const float*)d_in[11];
    const float* ln_ob      = (const float*)d_in[12];
    float* out = (float*)d_out;

    const int N = in_sizes[0] / 128;
    const int E = in_sizes[2];

    unsigned short* hvb = (unsigned short*)d_ws;        // N*64 bf16 (6.4 MB)
    unsigned short* hb  = hvb + (size_t)N * 64;         // N*64 bf16 (6.4 MB)

    hipMemsetAsync(hb, 0, (size_t)N * 64 * sizeof(unsigned short), stream);
    node_proj_kernel<<<784, 256, 0, stream>>>(node_feats, W_node, ln_ng, ln_nb, hvb, N);
    edge_kernel<<<1024, 256, 0, stream>>>(edge_feats, W_edge, ln_eg, ln_eb,
                                          src, dst, (const unsigned*)hvb, (unsigned*)hb, E);
    out_proj_kernel<<<784, 256, 0, stream>>>(hb, W_out, ln_og, ln_ob, out, N);
}